// Round 16
// baseline (3467.535 us; speedup 1.0000x reference)
//
#include <hip/hip_runtime.h>
#include <math.h>

#define cB 512
#define cS 256
#define cV 10
#define cE 128
#define cH 128
#define cD 256
#define cG 512   // 4*H
#define PEN 1.0e6f
#define PADK 40      // LDS row pitch in halfs for MFMA staging
#define S1OW 112     // ow head: cached s < S1OW (fp32), stripe len 144
#define L1OW 144
#define S2AT 128     // att head: cached s < S2AT (fp32), stripe len 128
#define L2AT 128

typedef _Float16 half8_t __attribute__((ext_vector_type(8)));
typedef _Float16 half4_t __attribute__((ext_vector_type(4)));
typedef float f32x4 __attribute__((ext_vector_type(4)));

#define DOT4(acc, wv, hv)                                   \
    do {                                                    \
        acc = fmaf((wv).x, (hv).x, acc);                    \
        acc = fmaf((wv).y, (hv).y, acc);                    \
        acc = fmaf((wv).z, (hv).z, acc);                    \
        acc = fmaf((wv).w, (hv).w, acc);                    \
    } while (0)

__device__ __forceinline__ float sigmf(float x) { return 1.0f / (1.0f + expf(-x)); }

// ---------------------------------------------------------------------------
// u = Wih @ emb. grid 2 x 512.  [verbatim]
// ---------------------------------------------------------------------------
__global__ void k_uprep(const float* __restrict__ Wih_f, const float* __restrict__ Wih_b,
                        const float* __restrict__ W_embed, float* __restrict__ uvec)
{
    const int j = threadIdx.x;
    const float* __restrict__ Wih = blockIdx.x ? Wih_b : Wih_f;
    float u = 0.f;
#pragma unroll 8
    for (int e = 0; e < cE; ++e) u = fmaf(Wih[(size_t)j * cE + e], W_embed[e], u);
    uvec[blockIdx.x * cG + j] = u;
}

// ---------------------------------------------------------------------------
// Encoder v4 (R11/R14 PASS, 663 us, VALUBusy 97% -- encoder roofline).
// ---------------------------------------------------------------------------
__global__ __launch_bounds__(1024, 2) void k_encoder(
    const float* __restrict__ s_inputs, const float* __restrict__ uvec,
    const float* __restrict__ Whh_f, const float* __restrict__ b_f,
    const float* __restrict__ Whh_b, const float* __restrict__ b_b,
    _Float16* __restrict__ Ehi, _Float16* __restrict__ Elo,
    float* __restrict__ h_state, float* __restrict__ c_state)
{
    const int dir = blockIdx.x >> 7;
    const int b0  = (blockIdx.x & 127) * 4;
    const float* __restrict__ Whh = dir ? Whh_b : Whh_f;
    const float* __restrict__ bv  = dir ? b_b   : b_f;
    const int tid = threadIdx.x;
    const int jj = tid & 255;    // gate pair: rows jj, jj+256
    const int q  = tid >> 8;     // k quarter (32 k)

    __shared__ __align__(16) float a_in[4][cS];
    __shared__ __align__(16) float hbuf[4][132];
    __shared__ __align__(16) float gpart[16][520];   // [r*4+q][gate]

    a_in[tid >> 8][tid & 255] =
        s_inputs[((size_t)(b0 + (tid >> 8)) * cS + (tid & 255)) * 3];

    float4 w0[8], w1[8];
#pragma unroll
    for (int kk = 0; kk < 8; ++kk) {
        w0[kk] = *(const float4*)&Whh[(size_t)jj * cH + q * 32 + kk * 4];
        w1[kk] = *(const float4*)&Whh[(size_t)(jj + 256) * cH + q * 32 + kk * 4];
    }

    const float uj0 = (q == 0) ? uvec[dir * cG + jj] : 0.f;
    const float bj0 = (q == 0) ? bv[jj] : 0.f;
    const float uj1 = (q == 0) ? uvec[dir * cG + jj + 256] : 0.f;
    const float bj1 = (q == 0) ? bv[jj + 256] : 0.f;

    const int ur = tid >> 7, uk = tid & 127;   // update role (tid < 512)
    float c_reg = 0.f, h_last = 0.f;
    if (tid < 512) hbuf[ur][uk] = 0.f;
    __syncthreads();

    for (int p = 0; p < cS; ++p) {
        const int s = dir ? (cS - 1 - p) : p;
        float a0[4], a1[4];
#pragma unroll
        for (int r = 0; r < 4; ++r) {
            a0[r] = fmaf(a_in[r][s], uj0, bj0);
            a1[r] = fmaf(a_in[r][s], uj1, bj1);
        }
#pragma unroll
        for (int kk = 0; kk < 8; ++kk) {
            const float4 wv0 = w0[kk];
            const float4 wv1 = w1[kk];
#pragma unroll
            for (int r = 0; r < 4; ++r) {
                const float4 h4 = *(const float4*)&hbuf[r][q * 32 + kk * 4];
                DOT4(a0[r], wv0, h4);
                DOT4(a1[r], wv1, h4);
            }
        }
#pragma unroll
        for (int r = 0; r < 4; ++r) {
            gpart[r * 4 + q][jj]       = a0[r];
            gpart[r * 4 + q][jj + 256] = a1[r];
        }
        __syncthreads();

        if (tid < 512) {
            float gi = 0.f, gf = 0.f, gg = 0.f, go = 0.f;
#pragma unroll
            for (int qq = 0; qq < 4; ++qq) {
                gi += gpart[ur * 4 + qq][uk];
                gf += gpart[ur * 4 + qq][128 + uk];
                gg += gpart[ur * 4 + qq][256 + uk];
                go += gpart[ur * 4 + qq][384 + uk];
            }
            const float i_ = sigmf(gi), f_ = sigmf(gf), g_ = tanhf(gg), o_ = sigmf(go);
            c_reg = fmaf(f_, c_reg, i_ * g_);
            const float hn = o_ * tanhf(c_reg);
            h_last = hn;
            hbuf[ur][uk] = hn;
            const size_t eidx = ((size_t)(b0 + ur) * cS + s) * cD + dir * cH + uk;
            const _Float16 hh = (_Float16)hn;
            Ehi[eidx] = hh;
            Elo[eidx] = (_Float16)(hn - (float)hh);
        }
        __syncthreads();
    }
    if (tid < 512) {
        h_state[((size_t)dir * cB + b0 + ur) * cH + uk] = h_last;
        c_state[((size_t)dir * cB + b0 + ur) * cH + uk] = c_reg;
    }
}

// ---------------------------------------------------------------------------
// fp16 split of the big attention weights (one-time).  [verbatim]
// ---------------------------------------------------------------------------
__global__ void k_split_w(const float* __restrict__ W1, const float* __restrict__ W2,
                          _Float16* __restrict__ Whi1, _Float16* __restrict__ Wlo1,
                          _Float16* __restrict__ Whi2, _Float16* __restrict__ Wlo2)
{
    const int i = blockIdx.x * 256 + threadIdx.x;   // grid 256 -> 65536
    {
        float a = W1[i]; _Float16 h = (_Float16)a;
        Whi1[i] = h; Wlo1[i] = (_Float16)(a - (float)h);
    }
    {
        float a = W2[i]; _Float16 h = (_Float16)a;
        Whi2[i] = h; Wlo2[i] = (_Float16)(a - (float)h);
    }
}

// ---------------------------------------------------------------------------
// One-time cache build, BOTH heads in one launch.  [R9/R11/R14 verbatim]
// ---------------------------------------------------------------------------
__global__ __launch_bounds__(256) void k_head_mat2(
    const _Float16* __restrict__ Ahi, const _Float16* __restrict__ Alo,
    const _Float16* __restrict__ Whi1, const _Float16* __restrict__ Wlo1,
    const _Float16* __restrict__ Whi2, const _Float16* __restrict__ Wlo2,
    float* __restrict__ refC, float* __restrict__ ref2C)
{
    const int blk = blockIdx.x;
    const bool is1 = blk < (S1OW * cB / 64);
    const _Float16* __restrict__ Whi = is1 ? Whi1 : Whi2;
    const _Float16* __restrict__ Wlo = is1 ? Wlo1 : Wlo2;
    float* __restrict__ outv = is1 ? refC : ref2C;
    const int m0 = (is1 ? blk : blk - S1OW * cB / 64) * 64;

    const int tid = threadIdx.x;
    const int w = tid >> 6, l = tid & 63;

    __shared__ __align__(16) _Float16 As[2][64][PADK];
    __shared__ __align__(16) _Float16 Ws[2][256][PADK];

    const int r = tid >> 2, kq = tid & 3;
    size_t arow;
    {
        const int m = m0 + r;
        const int s = m >> 9, b = m & 511;
        arow = ((size_t)b * cS + s) * cD;
    }
    const size_t wrow = (size_t)tid * cD;

    f32x4 acc[16];
#pragma unroll
    for (int i = 0; i < 16; ++i) acc[i] = (f32x4){0.f, 0.f, 0.f, 0.f};

    const int fr = w * 16 + (l & 15);
    const int kc = (l >> 4) * 8;

    for (int k0 = 0; k0 < 256; k0 += 32) {
        __syncthreads();
        *(uint4*)&As[0][r][kq * 8] = *(const uint4*)&Ahi[arow + k0 + kq * 8];
        *(uint4*)&As[1][r][kq * 8] = *(const uint4*)&Alo[arow + k0 + kq * 8];
#pragma unroll
        for (int q4 = 0; q4 < 4; ++q4) {
            *(uint4*)&Ws[0][tid][q4 * 8] = *(const uint4*)&Whi[wrow + k0 + q4 * 8];
            *(uint4*)&Ws[1][tid][q4 * 8] = *(const uint4*)&Wlo[wrow + k0 + q4 * 8];
        }
        __syncthreads();

        const half8_t ahi = *(const half8_t*)&As[0][fr][kc];
        const half8_t alo = *(const half8_t*)&As[1][fr][kc];
#pragma unroll
        for (int nf = 0; nf < 16; ++nf) {
            const int n = nf * 16 + (l & 15);
            const half8_t bhi = *(const half8_t*)&Ws[0][n][kc];
            const half8_t blo = *(const half8_t*)&Ws[1][n][kc];
            acc[nf] = __builtin_amdgcn_mfma_f32_16x16x32_f16(ahi, bhi, acc[nf], 0, 0, 0);
            acc[nf] = __builtin_amdgcn_mfma_f32_16x16x32_f16(ahi, blo, acc[nf], 0, 0, 0);
            acc[nf] = __builtin_amdgcn_mfma_f32_16x16x32_f16(alo, bhi, acc[nf], 0, 0, 0);
        }
    }
#pragma unroll
    for (int nf = 0; nf < 16; ++nf)
#pragma unroll
        for (int rr = 0; rr < 4; ++rr) {
            const int m = w * 16 + ((l >> 4) << 2) + rr;
            outv[(size_t)(m0 + m) * cD + nf * 16 + (l & 15)] = acc[nf][rr];
        }
}

// ---------------------------------------------------------------------------
// MEGA score kernel  [R9/R11/R14 verbatim — the 3.00 ms pass]
// ---------------------------------------------------------------------------
__global__ __launch_bounds__(512, 2) void k_score(
    const _Float16* __restrict__ Ahi, const _Float16* __restrict__ Alo,
    const _Float16* __restrict__ Whi1, const _Float16* __restrict__ Wlo1,
    const _Float16* __restrict__ Whi2, const _Float16* __restrict__ Wlo2,
    const float* __restrict__ refC, const float* __restrict__ ref2C,
    const float* __restrict__ q1v, const float* __restrict__ q2v,
    const float* __restrict__ v_w, const float* __restrict__ v2_w,
    float* __restrict__ sc1lo, float* __restrict__ sc1hi,
    float* __restrict__ sc2lo, float* __restrict__ sc2hi)
{
    __shared__ __align__(16) char smem[65536];
    const int blk = blockIdx.x;
    const int tid = threadIdx.x;

    if (blk < 1088) {
        // ------------------------- stripe branch --------------------------
        const bool isow = blk < 576;
        const _Float16* __restrict__ Whi = isow ? Whi1 : Whi2;
        const _Float16* __restrict__ Wlo = isow ? Wlo1 : Wlo2;
        const int batt = blk - 576;
        const int m0 = isow ? blk * 128 : 0;

        _Float16 (*Ah)[PADK] = (_Float16(*)[PADK])(smem);
        _Float16 (*Al)[PADK] = (_Float16(*)[PADK])(smem + 10240);
        _Float16 (*Wh)[PADK] = (_Float16(*)[PADK])(smem + 20480);
        _Float16 (*Wl)[PADK] = (_Float16(*)[PADK])(smem + 40960);
        float* qs = (float*)(smem + 61440);
        float* vs = (float*)(smem + 62464);
        float (*spart)[128] = (float(*)[128])(smem + 63488);

        const int l = tid & 63;
        const int w = tid >> 6;
        const int wm = w >> 2, wn = w & 3;
        const int g = l >> 4, li = l & 15;

        if (isow) {
            if (tid < 256) vs[tid] = v_w[tid];
        } else {
            if (tid < 256) qs[tid] = q2v[(size_t)batt * cD + tid];
            else           vs[tid - 256] = v2_w[tid - 256];
        }

        const int ar = tid >> 2, aq = tid & 3;
        size_t arow;
        if (isow) {
            const int m = m0 + ar;
            const int bq = m / L1OW;
            const int s = S1OW + (m - bq * L1OW);
            arow = ((size_t)bq * cS + s) * cD;
        } else {
            arow = ((size_t)batt * cS + S2AT + ar) * cD;
        }

        f32x4 acc[4][4];
#pragma unroll
        for (int mi = 0; mi < 4; ++mi)
#pragma unroll
            for (int ni = 0; ni < 4; ++ni) acc[mi][ni] = (f32x4){0.f, 0.f, 0.f, 0.f};

        for (int k0 = 0; k0 < 256; k0 += 32) {
            __syncthreads();
            *(uint4*)&Ah[ar][aq * 8] = *(const uint4*)&Ahi[arow + k0 + aq * 8];
            *(uint4*)&Al[ar][aq * 8] = *(const uint4*)&Alo[arow + k0 + aq * 8];
            *(uint4*)&Wh[ar][aq * 8] = *(const uint4*)&Whi[(size_t)ar * cD + k0 + aq * 8];
            *(uint4*)&Wl[ar][aq * 8] = *(const uint4*)&Wlo[(size_t)ar * cD + k0 + aq * 8];
            *(uint4*)&Wh[ar + 128][aq * 8] = *(const uint4*)&Whi[(size_t)(ar + 128) * cD + k0 + aq * 8];
            *(uint4*)&Wl[ar + 128][aq * 8] = *(const uint4*)&Wlo[(size_t)(ar + 128) * cD + k0 + aq * 8];
            __syncthreads();

            half8_t ah[4], al[4];
#pragma unroll
            for (int mi = 0; mi < 4; ++mi) {
                ah[mi] = *(const half8_t*)&Ah[wm * 64 + mi * 16 + li][g * 8];
                al[mi] = *(const half8_t*)&Al[wm * 64 + mi * 16 + li][g * 8];
            }
#pragma unroll
            for (int ni = 0; ni < 4; ++ni) {
                const half8_t bh = *(const half8_t*)&Wh[wn * 64 + ni * 16 + li][g * 8];
                const half8_t bl = *(const half8_t*)&Wl[wn * 64 + ni * 16 + li][g * 8];
#pragma unroll
                for (int mi = 0; mi < 4; ++mi) {
                    acc[mi][ni] = __builtin_amdgcn_mfma_f32_16x16x32_f16(ah[mi], bh, acc[mi][ni], 0, 0, 0);
                    acc[mi][ni] = __builtin_amdgcn_mfma_f32_16x16x32_f16(ah[mi], bl, acc[mi][ni], 0, 0, 0);
                    acc[mi][ni] = __builtin_amdgcn_mfma_f32_16x16x32_f16(al[mi], bh, acc[mi][ni], 0, 0, 0);
                }
            }
        }

        float val = 0.f;
#pragma unroll
        for (int mi = 0; mi < 4; ++mi)
#pragma unroll
            for (int rr = 0; rr < 4; ++rr) {
                const int row = wm * 64 + mi * 16 + g * 4 + rr;
                float p = 0.f;
#pragma unroll
                for (int ni = 0; ni < 4; ++ni) {
                    const int c = wn * 64 + ni * 16 + li;
                    const float qq = isow ? q1v[(size_t)((m0 + row) / L1OW) * cD + c]
                                          : qs[c];
                    p = fmaf(vs[c], tanhf(acc[mi][ni][rr] + qq), p);
                }
                p += __shfl_xor(p, 1);
                p += __shfl_xor(p, 2);
                p += __shfl_xor(p, 4);
                p += __shfl_xor(p, 8);
                if (li == mi * 4 + rr) val = p;
            }
        {
            const int row_out = wm * 64 + (li >> 2) * 16 + g * 4 + (li & 3);
            spart[wn][row_out] = val;
        }
        __syncthreads();
        if (tid < 128) {
            const float o = spart[0][tid] + spart[1][tid] + spart[2][tid] + spart[3][tid];
            if (isow) sc1hi[m0 + tid] = o;
            else      sc2hi[(size_t)batt * L2AT + tid] = o;
        }
    } else {
        // -------------------------- fold branch ---------------------------
        const int fb = blk - 1088;
        const bool isowf = fb < 448;           // 448 = S1OW*cB/128
        const float* __restrict__ C  = isowf ? refC : ref2C;
        const float* __restrict__ qv = isowf ? q1v : q2v;
        const float* __restrict__ vv = isowf ? v_w : v2_w;
        float* __restrict__ outv     = isowf ? sc1lo : sc2lo;
        const int m0 = (isowf ? fb : fb - 448) * 128;

        float (*red)[4] = (float(*)[4])smem;
        const int r = tid >> 2, p2 = tid & 3;
        const int m = m0 + r;
        const int b = m & 511;

        const float* row  = C + (size_t)m * cD + p2 * 64;
        const float* qrow = qv + (size_t)b * cD + p2 * 64;
        const float* vrow = vv + p2 * 64;
        float s = 0.f;
#pragma unroll 4
        for (int d = 0; d < 64; d += 4) {
            const float4 rv4 = *(const float4*)&row[d];
            const float4 q4  = *(const float4*)&qrow[d];
            const float4 v4  = *(const float4*)&vrow[d];
            s = fmaf(v4.x, tanhf(rv4.x + q4.x), s);
            s = fmaf(v4.y, tanhf(rv4.y + q4.y), s);
            s = fmaf(v4.z, tanhf(rv4.z + q4.z), s);
            s = fmaf(v4.w, tanhf(rv4.w + q4.w), s);
        }
        red[r][p2] = s;
        __syncthreads();
        if (tid < 128)
            outv[m0 + tid] = red[tid][0] + red[tid][1] + red[tid][2] + red[tid][3];
    }
}

// ---------------------------------------------------------------------------
// MERGED decoder cells + q projections (bit-identical math to the R14 pair).
// grid = 128 (4 batch rows each), block = 1024: threads 0-511 forward cell,
// 512-1023 backward cell; qproj phase reuses LDS dout/xin.
// ---------------------------------------------------------------------------
__global__ __launch_bounds__(1024, 4) void k_cells_qp(
    const float* __restrict__ dec_in,
    const float* __restrict__ Wih_f, const float* __restrict__ Whh_f, const float* __restrict__ b_f,
    const float* __restrict__ Wih_b, const float* __restrict__ Whh_b, const float* __restrict__ b_b,
    const float* __restrict__ W_q, const float* __restrict__ W_q2,
    float* __restrict__ h_state, float* __restrict__ c_state, float* __restrict__ dec_out,
    float* __restrict__ q1v, float* __restrict__ q2v)
{
    const int b0 = blockIdx.x * 4;
    const int tid = threadIdx.x;
    const int cell = tid >> 9;       // 0 = forward, 1 = backward
    const int j = tid & 511;         // gate row within cell

    const float* __restrict__ Wih = cell ? Wih_b : Wih_f;
    const float* __restrict__ Whh = cell ? Whh_b : Whh_f;
    const float* __restrict__ bv  = cell ? b_b   : b_f;

    __shared__ __align__(16) float xin[4][cD];       // 4 KB
    __shared__ __align__(16) float hin[2][4][cH];    // 4 KB
    __shared__ __align__(16) float gbuf[2][4][cG];   // 16 KB
    __shared__ __align__(16) float dout[4][cD];      // 4 KB

    {
        const int bb = tid >> 8, k = tid & 255;      // covers 4x256 exactly... (tid<1024)
        if (tid < 1024) xin[bb & 3][k] = dec_in[(size_t)(b0 + (bb & 3)) * cD + k];
    }
    {
        const int c2 = tid >> 9, bb = (tid >> 7) & 3, k = tid & 127;
        hin[c2][bb][k] = h_state[((size_t)c2 * cB + b0 + bb) * cH + k];
    }
    __syncthreads();

    // gate dots -- per-thread chain identical to R14 k_dec_cells
    float a0 = bv[j];
    float a1 = a0, a2 = a0, a3 = a0;
#pragma unroll 4
    for (int kk = 0; kk < 64; ++kk) {
        const float4 wv = *(const float4*)&Wih[(size_t)j * cD + kk * 4];
        const float4 x0 = *(const float4*)&xin[0][kk * 4]; DOT4(a0, wv, x0);
        const float4 x1 = *(const float4*)&xin[1][kk * 4]; DOT4(a1, wv, x1);
        const float4 x2 = *(const float4*)&xin[2][kk * 4]; DOT4(a2, wv, x2);
        const float4 x3 = *(const float4*)&xin[3][kk * 4]; DOT4(a3, wv, x3);
    }
#pragma unroll 4
    for (int kk = 0; kk < 32; ++kk) {
        const float4 wv = *(const float4*)&Whh[(size_t)j * cH + kk * 4];
        const float4 h0 = *(const float4*)&hin[cell][0][kk * 4]; DOT4(a0, wv, h0);
        const float4 h1 = *(const float4*)&hin[cell][1][kk * 4]; DOT4(a1, wv, h1);
        const float4 h2 = *(const float4*)&hin[cell][2][kk * 4]; DOT4(a2, wv, h2);
        const float4 h3 = *(const float4*)&hin[cell][3][kk * 4]; DOT4(a3, wv, h3);
    }
    gbuf[cell][0][j] = a0; gbuf[cell][1][j] = a1;
    gbuf[cell][2][j] = a2; gbuf[cell][3][j] = a3;
    __syncthreads();

    // LSTM update: thread -> (c2, ub, uk); math identical to R14
    {
        const int c2 = tid >> 9, ub = (tid >> 7) & 3, uk = tid & 127;
        const float gi = gbuf[c2][ub][uk];
        const float gf = gbuf[c2][ub][128 + uk];
        const float gg = gbuf[c2][ub][256 + uk];
        const float go = gbuf[c2][ub][384 + uk];
        const size_t sidx = ((size_t)c2 * cB + b0 + ub) * cH + uk;
        const float c_old = c_state[sidx];
        const float i_ = sigmf(gi), f_ = sigmf(gf), g_ = tanhf(gg), o_ = sigmf(go);
        const float cn = fmaf(f_, c_old, i_ * g_);
        const float hn = o_ * tanhf(cn);
        c_state[sidx] = cn;
        h_state[sidx] = hn;
        dec_out[(size_t)(b0 + ub) * cD + c2 * cH + uk] = hn;
        dout[ub][c2 * cH + uk] = hn;
    }
    __syncthreads();

    // q projections: thread -> (bb, d); chain identical to R14 k_qproj
    {
        const int bb = tid >> 8, d = tid & 255;
        float s1 = 0.0f, s2 = 0.0f;
#pragma unroll 4
        for (int kk = 0; kk < 64; ++kk) {
            const float4 w1 = *(const float4*)&W_q[(size_t)d * cD + kk * 4];
            const float4 w2 = *(const float4*)&W_q2[(size_t)d * cD + kk * 4];
            const float4 x1 = *(const float4*)&dout[bb][kk * 4];
            const float4 x2 = *(const float4*)&xin[bb][kk * 4];
            DOT4(s1, w1, x1);
            DOT4(s2, w2, x2);
        }
        q1v[(size_t)(b0 + bb) * cD + d] = s1;
        q2v[(size_t)(b0 + bb) * cD + d] = s2;
    }
}

// ---------------------------------------------------------------------------
// Finish step.  [R14 verbatim]
// ---------------------------------------------------------------------------
__global__ __launch_bounds__(256, 2) void k_finish(
    const float* __restrict__ sc1lo, const float* __restrict__ sc1hi,
    const float* __restrict__ sc2lo, const float* __restrict__ sc2hi,
    const _Float16* __restrict__ Ehi, const _Float16* __restrict__ Elo,
    const float* __restrict__ s_inputs, const int* __restrict__ s_node_indexes,
    const float* __restrict__ v_input, float* __restrict__ played,
    float* __restrict__ dec_in_new, float* __restrict__ outp, int t)
{
    const int b = blockIdx.x;
    const int tid = threadIdx.x;
    const int lane = tid & 63;
    const int wv = tid >> 6;

    __shared__ __align__(16) float atr[cS];
    __shared__ __align__(16) float part[4][cD];
    __shared__ float rv[cS];
    __shared__ int   ri[cS];

    const float owv = (tid < S1OW) ? sc1lo[(size_t)tid * cB + b]
                                   : sc1hi[(size_t)b * L1OW + (tid - S1OW)];
    atr[tid] = (tid < S2AT) ? sc2lo[(size_t)tid * cB + b]
                            : sc2hi[(size_t)b * L2AT + (tid - S2AT)];

    const float vcpu = v_input[t * 3];
    float val;
    {
        const float a0 = s_inputs[((size_t)b * cS + tid) * 3];
        const float can = (a0 < vcpu ? 1.0f : 0.0f) + played[(size_t)b * cS + tid];
        val = owv - PEN * can;
        outp[2 * cB * cV + ((size_t)t * cB + b) * cS + tid] = val;
    }
    rv[tid] = val; ri[tid] = tid;
    __syncthreads();
#pragma unroll
    for (int off = 128; off > 0; off >>= 1) {
        if (tid < off) {
            const float v2 = rv[tid + off]; const int i2 = ri[tid + off];
            const float v1 = rv[tid];       const int i1 = ri[tid];
            if (v2 > v1 || (v2 == v1 && i2 < i1)) { rv[tid] = v2; ri[tid] = i2; }
        }
        __syncthreads();
    }
    const int sel = ri[0];
    __syncthreads();
    if (tid == 0) {
        played[(size_t)b * cS + sel] += 1.0f;
        outp[(size_t)b * cV + t] = (float)s_node_indexes[(size_t)b * cS + sel];
        outp[(size_t)cB * cV + (size_t)b * cV + t] = (float)sel;
    }

    rv[tid] = atr[tid];
    __syncthreads();
#pragma unroll
    for (int off = 128; off > 0; off >>= 1) {
        if (tid < off) { const float v2 = rv[tid + off]; if (v2 > rv[tid]) rv[tid] = v2; }
        __syncthreads();
    }
    const float mx = rv[0];
    __syncthreads();
    const float ex = expf(atr[tid] - mx);
    rv[tid] = ex;
    __syncthreads();
#pragma unroll
    for (int off = 128; off > 0; off >>= 1) {
        if (tid < off) rv[tid] += rv[tid + off];
        __syncthreads();
    }
    const float ssum = rv[0];
    __syncthreads();
    atr[tid] = ex / ssum;
    __syncthreads();

    {
        float4 acc = make_float4(0.f, 0.f, 0.f, 0.f);
        for (int s2i = wv * 64; s2i < wv * 64 + 64; ++s2i) {
            const float a = atr[s2i];
            const size_t eidx = ((size_t)b * cS + s2i) * cD + lane * 4;
            const half4_t h4 = *(const half4_t*)&Ehi[eidx];
            const half4_t l4 = *(const half4_t*)&Elo[eidx];
            acc.x = fmaf(a, (float)h4[0] + (float)l4[0], acc.x);
            acc.y = fmaf(a, (float)h4[1] + (float)l4[1], acc.y);
            acc.z = fmaf(a, (float)h4[2] + (float)l4[2], acc.z);
            acc.w = fmaf(a, (float)h4[3] + (float)l4[3], acc.w);
        }
        *(float4*)&part[wv][lane * 4] = acc;
    }
    __syncthreads();
    dec_in_new[(size_t)b * cD + tid] =
        part[0][tid] + part[1][tid] + part[2][tid] + part[3][tid];
}

// ---------------------------------------------------------------------------
extern "C" void kernel_launch(void* const* d_in, const int* in_sizes, int n_in,
                              void* d_out, int out_size, void* d_ws, size_t ws_size,
                              hipStream_t stream)
{
    (void)in_sizes; (void)n_in; (void)out_size; (void)ws_size;

    const int*   s_node = (const int*)  d_in[0];
    const float* s_inp  = (const float*)d_in[1];
    const float* v_inp  = (const float*)d_in[2];
    const float* W_emb  = (const float*)d_in[3];
    const float* eWih_f = (const float*)d_in[4];
    const float* eWhh_f = (const float*)d_in[5];
    const float* eb_f   = (const float*)d_in[6];
    const float* eWih_b = (const float*)d_in[7];
    const float* eWhh_b = (const float*)d_in[8];
    const float* eb_b   = (const float*)d_in[9];
    const float* dWih_f = (const float*)d_in[10];
    const float* dWhh_f = (const float*)d_in[11];
    const float* db_f   = (const float*)d_in[12];
    const float* dWih_b = (const float*)d_in[13];
    const float* dWhh_b = (const float*)d_in[14];
    const float* db_b   = (const float*)d_in[15];
    const float* W_ref  = (const float*)d_in[16];
    const float* W_q    = (const float*)d_in[17];
    const float* v_w    = (const float*)d_in[18];
    const float* W_ref2 = (const float*)d_in[19];
    const float* W_q2   = (const float*)d_in[20];
    const float* v2_w   = (const float*)d_in[21];

    float* out = (float*)d_out;
    const size_t ENCSZ = (size_t)cB * cS * cD;     // 33,554,432 elements
    const size_t SMALL = (size_t)cB * cD;          // 131,072 floats

    // layout (bytes), total ~253.5 MiB <= 255 MiB  [R14 verbatim]
    char* p = (char*)d_ws;
    _Float16* Ehi  = (_Float16*)p; p += ENCSZ * 2;
    _Float16* Elo  = (_Float16*)p; p += ENCSZ * 2;
    float* refC    = (float*)p;    p += (size_t)S1OW * cB * cD * 4;
    float* ref2C   = (float*)p;    p += (size_t)S2AT * cB * cD * 4;
    _Float16* Whi1 = (_Float16*)p; p += (size_t)cD * cD * 2;
    _Float16* Wlo1 = (_Float16*)p; p += (size_t)cD * cD * 2;
    _Float16* Whi2 = (_Float16*)p; p += (size_t)cD * cD * 2;
    _Float16* Wlo2 = (_Float16*)p; p += (size_t)cD * cD * 2;
    float* hst    = (float*)p; p += SMALL * 4;
    float* cst    = (float*)p; p += SMALL * 4;
    float* din0   = (float*)p; p += SMALL * 4;
    float* din1   = (float*)p; p += SMALL * 4;
    float* doutb  = (float*)p; p += SMALL * 4;
    float* played = (float*)p; p += SMALL * 4;
    float* q1v    = (float*)p; p += SMALL * 4;
    float* q2v    = (float*)p; p += SMALL * 4;
    float* sc1lo  = (float*)p; p += (size_t)S1OW * cB * 4;
    float* sc1hi  = (float*)p; p += (size_t)L1OW * cB * 4;
    float* sc2lo  = (float*)p; p += (size_t)S2AT * cB * 4;
    float* sc2hi  = (float*)p; p += (size_t)L2AT * cB * 4;
    float* uvec   = (float*)p; p += 2 * cG * 4;

    hipMemsetAsync(played, 0, SMALL * sizeof(float), stream);
    hipMemsetAsync(din0,   0, SMALL * sizeof(float), stream);

    k_split_w<<<256, 256, 0, stream>>>(W_ref, W_ref2, Whi1, Wlo1, Whi2, Wlo2);
    k_uprep<<<2, 512, 0, stream>>>(eWih_f, eWih_b, W_emb, uvec);

    k_encoder<<<256, 1024, 0, stream>>>(s_inp, uvec, eWhh_f, eb_f, eWhh_b, eb_b,
                                        Ehi, Elo, hst, cst);

    // one-time fp32 caches, both heads in one launch (bit-exact)
    k_head_mat2<<<(S1OW + S2AT) * cB / 64, 256, 0, stream>>>(
        Ehi, Elo, Whi1, Wlo1, Whi2, Wlo2, refC, ref2C);

    for (int t = 0; t < cV; ++t) {
        float* di_old = (t & 1) ? din1 : din0;
        float* di_new = (t & 1) ? din0 : din1;
        k_cells_qp<<<128, 1024, 0, stream>>>(di_old, dWih_f, dWhh_f, db_f,
                                             dWih_b, dWhh_b, db_b, W_q, W_q2,
                                             hst, cst, doutb, q1v, q2v);
        k_score<<<2048, 512, 0, stream>>>(Ehi, Elo, Whi1, Wlo1, Whi2, Wlo2,
                                          refC, ref2C, q1v, q2v, v_w, v2_w,
                                          sc1lo, sc1hi, sc2lo, sc2hi);
        k_finish<<<512, 256, 0, stream>>>(sc1lo, sc1hi, sc2lo, sc2hi, Ehi, Elo,
                                          s_inp, s_node, v_inp, played, di_new, out, t);
    }
}

// Round 17
// 2978.070 us; speedup vs baseline: 1.1644x; 1.1644x over previous
//
#include <hip/hip_runtime.h>
#include <math.h>

#define cB 512
#define cS 256
#define cV 10
#define cE 128
#define cH 128
#define cD 256
#define cG 512   // 4*H
#define PEN 1.0e6f
#define PADK 40      // LDS row pitch in halfs for MFMA staging
#define S1OW 112     // ow head: cached s < S1OW (fp32), stripe len 144
#define L1OW 144
#define S2AT 128     // att head: cached s < S2AT (fp32), stripe len 128
#define L2AT 128

typedef _Float16 half8_t __attribute__((ext_vector_type(8)));
typedef _Float16 half4_t __attribute__((ext_vector_type(4)));
typedef float f32x4 __attribute__((ext_vector_type(4)));

#define DOT4(acc, wv, hv)                                   \
    do {                                                    \
        acc = fmaf((wv).x, (hv).x, acc);                    \
        acc = fmaf((wv).y, (hv).y, acc);                    \
        acc = fmaf((wv).z, (hv).z, acc);                    \
        acc = fmaf((wv).w, (hv).w, acc);                    \
    } while (0)

__device__ __forceinline__ float sigmf(float x) { return 1.0f / (1.0f + expf(-x)); }

// ---------------------------------------------------------------------------
// u = Wih @ emb. grid 2 x 512.
// ---------------------------------------------------------------------------
__global__ void k_uprep(const float* __restrict__ Wih_f, const float* __restrict__ Wih_b,
                        const float* __restrict__ W_embed, float* __restrict__ uvec)
{
    const int j = threadIdx.x;
    const float* __restrict__ Wih = blockIdx.x ? Wih_b : Wih_f;
    float u = 0.f;
#pragma unroll 8
    for (int e = 0; e < cE; ++e) u = fmaf(Wih[(size_t)j * cE + e], W_embed[e], u);
    uvec[blockIdx.x * cG + j] = u;
}

// ---------------------------------------------------------------------------
// Encoder v4 (R11/R14 PASS, 663 us, VALUBusy 97% -- encoder roofline).
// ---------------------------------------------------------------------------
__global__ __launch_bounds__(1024, 2) void k_encoder(
    const float* __restrict__ s_inputs, const float* __restrict__ uvec,
    const float* __restrict__ Whh_f, const float* __restrict__ b_f,
    const float* __restrict__ Whh_b, const float* __restrict__ b_b,
    _Float16* __restrict__ Ehi, _Float16* __restrict__ Elo,
    float* __restrict__ h_state, float* __restrict__ c_state)
{
    const int dir = blockIdx.x >> 7;
    const int b0  = (blockIdx.x & 127) * 4;
    const float* __restrict__ Whh = dir ? Whh_b : Whh_f;
    const float* __restrict__ bv  = dir ? b_b   : b_f;
    const int tid = threadIdx.x;
    const int jj = tid & 255;    // gate pair: rows jj, jj+256
    const int q  = tid >> 8;     // k quarter (32 k)

    __shared__ __align__(16) float a_in[4][cS];
    __shared__ __align__(16) float hbuf[4][132];
    __shared__ __align__(16) float gpart[16][520];   // [r*4+q][gate]

    a_in[tid >> 8][tid & 255] =
        s_inputs[((size_t)(b0 + (tid >> 8)) * cS + (tid & 255)) * 3];

    float4 w0[8], w1[8];
#pragma unroll
    for (int kk = 0; kk < 8; ++kk) {
        w0[kk] = *(const float4*)&Whh[(size_t)jj * cH + q * 32 + kk * 4];
        w1[kk] = *(const float4*)&Whh[(size_t)(jj + 256) * cH + q * 32 + kk * 4];
    }

    const float uj0 = (q == 0) ? uvec[dir * cG + jj] : 0.f;
    const float bj0 = (q == 0) ? bv[jj] : 0.f;
    const float uj1 = (q == 0) ? uvec[dir * cG + jj + 256] : 0.f;
    const float bj1 = (q == 0) ? bv[jj + 256] : 0.f;

    const int ur = tid >> 7, uk = tid & 127;   // update role (tid < 512)
    float c_reg = 0.f, h_last = 0.f;
    if (tid < 512) hbuf[ur][uk] = 0.f;
    __syncthreads();

    for (int p = 0; p < cS; ++p) {
        const int s = dir ? (cS - 1 - p) : p;
        float a0[4], a1[4];
#pragma unroll
        for (int r = 0; r < 4; ++r) {
            a0[r] = fmaf(a_in[r][s], uj0, bj0);
            a1[r] = fmaf(a_in[r][s], uj1, bj1);
        }
#pragma unroll
        for (int kk = 0; kk < 8; ++kk) {
            const float4 wv0 = w0[kk];
            const float4 wv1 = w1[kk];
#pragma unroll
            for (int r = 0; r < 4; ++r) {
                const float4 h4 = *(const float4*)&hbuf[r][q * 32 + kk * 4];
                DOT4(a0[r], wv0, h4);
                DOT4(a1[r], wv1, h4);
            }
        }
#pragma unroll
        for (int r = 0; r < 4; ++r) {
            gpart[r * 4 + q][jj]       = a0[r];
            gpart[r * 4 + q][jj + 256] = a1[r];
        }
        __syncthreads();

        if (tid < 512) {
            float gi = 0.f, gf = 0.f, gg = 0.f, go = 0.f;
#pragma unroll
            for (int qq = 0; qq < 4; ++qq) {
                gi += gpart[ur * 4 + qq][uk];
                gf += gpart[ur * 4 + qq][128 + uk];
                gg += gpart[ur * 4 + qq][256 + uk];
                go += gpart[ur * 4 + qq][384 + uk];
            }
            const float i_ = sigmf(gi), f_ = sigmf(gf), g_ = tanhf(gg), o_ = sigmf(go);
            c_reg = fmaf(f_, c_reg, i_ * g_);
            const float hn = o_ * tanhf(c_reg);
            h_last = hn;
            hbuf[ur][uk] = hn;
            const size_t eidx = ((size_t)(b0 + ur) * cS + s) * cD + dir * cH + uk;
            const _Float16 hh = (_Float16)hn;
            Ehi[eidx] = hh;
            Elo[eidx] = (_Float16)(hn - (float)hh);
        }
        __syncthreads();
    }
    if (tid < 512) {
        h_state[((size_t)dir * cB + b0 + ur) * cH + uk] = h_last;
        c_state[((size_t)dir * cB + b0 + ur) * cH + uk] = c_reg;
    }
}

// ---------------------------------------------------------------------------
// fp16 split of the big attention weights (one-time).
// ---------------------------------------------------------------------------
__global__ void k_split_w(const float* __restrict__ W1, const float* __restrict__ W2,
                          _Float16* __restrict__ Whi1, _Float16* __restrict__ Wlo1,
                          _Float16* __restrict__ Whi2, _Float16* __restrict__ Wlo2)
{
    const int i = blockIdx.x * 256 + threadIdx.x;   // grid 256 -> 65536
    {
        float a = W1[i]; _Float16 h = (_Float16)a;
        Whi1[i] = h; Wlo1[i] = (_Float16)(a - (float)h);
    }
    {
        float a = W2[i]; _Float16 h = (_Float16)a;
        Whi2[i] = h; Wlo2[i] = (_Float16)(a - (float)h);
    }
}

// ---------------------------------------------------------------------------
// One-time cache build, BOTH heads in one launch.
// ---------------------------------------------------------------------------
__global__ __launch_bounds__(256) void k_head_mat2(
    const _Float16* __restrict__ Ahi, const _Float16* __restrict__ Alo,
    const _Float16* __restrict__ Whi1, const _Float16* __restrict__ Wlo1,
    const _Float16* __restrict__ Whi2, const _Float16* __restrict__ Wlo2,
    float* __restrict__ refC, float* __restrict__ ref2C)
{
    const int blk = blockIdx.x;
    const bool is1 = blk < (S1OW * cB / 64);
    const _Float16* __restrict__ Whi = is1 ? Whi1 : Whi2;
    const _Float16* __restrict__ Wlo = is1 ? Wlo1 : Wlo2;
    float* __restrict__ outv = is1 ? refC : ref2C;
    const int m0 = (is1 ? blk : blk - S1OW * cB / 64) * 64;

    const int tid = threadIdx.x;
    const int w = tid >> 6, l = tid & 63;

    __shared__ __align__(16) _Float16 As[2][64][PADK];
    __shared__ __align__(16) _Float16 Ws[2][256][PADK];

    const int r = tid >> 2, kq = tid & 3;
    size_t arow;
    {
        const int m = m0 + r;
        const int s = m >> 9, b = m & 511;
        arow = ((size_t)b * cS + s) * cD;
    }
    const size_t wrow = (size_t)tid * cD;

    f32x4 acc[16];
#pragma unroll
    for (int i = 0; i < 16; ++i) acc[i] = (f32x4){0.f, 0.f, 0.f, 0.f};

    const int fr = w * 16 + (l & 15);
    const int kc = (l >> 4) * 8;

    for (int k0 = 0; k0 < 256; k0 += 32) {
        __syncthreads();
        *(uint4*)&As[0][r][kq * 8] = *(const uint4*)&Ahi[arow + k0 + kq * 8];
        *(uint4*)&As[1][r][kq * 8] = *(const uint4*)&Alo[arow + k0 + kq * 8];
#pragma unroll
        for (int q4 = 0; q4 < 4; ++q4) {
            *(uint4*)&Ws[0][tid][q4 * 8] = *(const uint4*)&Whi[wrow + k0 + q4 * 8];
            *(uint4*)&Ws[1][tid][q4 * 8] = *(const uint4*)&Wlo[wrow + k0 + q4 * 8];
        }
        __syncthreads();

        const half8_t ahi = *(const half8_t*)&As[0][fr][kc];
        const half8_t alo = *(const half8_t*)&As[1][fr][kc];
#pragma unroll
        for (int nf = 0; nf < 16; ++nf) {
            const int n = nf * 16 + (l & 15);
            const half8_t bhi = *(const half8_t*)&Ws[0][n][kc];
            const half8_t blo = *(const half8_t*)&Ws[1][n][kc];
            acc[nf] = __builtin_amdgcn_mfma_f32_16x16x32_f16(ahi, bhi, acc[nf], 0, 0, 0);
            acc[nf] = __builtin_amdgcn_mfma_f32_16x16x32_f16(ahi, blo, acc[nf], 0, 0, 0);
            acc[nf] = __builtin_amdgcn_mfma_f32_16x16x32_f16(alo, bhi, acc[nf], 0, 0, 0);
        }
    }
#pragma unroll
    for (int nf = 0; nf < 16; ++nf)
#pragma unroll
        for (int rr = 0; rr < 4; ++rr) {
            const int m = w * 16 + ((l >> 4) << 2) + rr;
            outv[(size_t)(m0 + m) * cD + nf * 16 + (l & 15)] = acc[nf][rr];
        }
}

// ---------------------------------------------------------------------------
// MEGA score kernel  [the 3.00 ms pass]:
//   blk <  576 : ow stripe  (s in [S1OW,256), rows m = b*L1OW + (s-S1OW))
//   blk < 1088 : att stripe (b = blk-576, s in [S2AT,256))
//   else       : folds over fp32 caches (448 ow blocks + 512 att blocks)
// ---------------------------------------------------------------------------
__global__ __launch_bounds__(512, 2) void k_score(
    const _Float16* __restrict__ Ahi, const _Float16* __restrict__ Alo,
    const _Float16* __restrict__ Whi1, const _Float16* __restrict__ Wlo1,
    const _Float16* __restrict__ Whi2, const _Float16* __restrict__ Wlo2,
    const float* __restrict__ refC, const float* __restrict__ ref2C,
    const float* __restrict__ q1v, const float* __restrict__ q2v,
    const float* __restrict__ v_w, const float* __restrict__ v2_w,
    float* __restrict__ sc1lo, float* __restrict__ sc1hi,
    float* __restrict__ sc2lo, float* __restrict__ sc2hi)
{
    __shared__ __align__(16) char smem[65536];
    const int blk = blockIdx.x;
    const int tid = threadIdx.x;

    if (blk < 1088) {
        // ------------------------- stripe branch --------------------------
        const bool isow = blk < 576;
        const _Float16* __restrict__ Whi = isow ? Whi1 : Whi2;
        const _Float16* __restrict__ Wlo = isow ? Wlo1 : Wlo2;
        const int batt = blk - 576;
        const int m0 = isow ? blk * 128 : 0;

        _Float16 (*Ah)[PADK] = (_Float16(*)[PADK])(smem);
        _Float16 (*Al)[PADK] = (_Float16(*)[PADK])(smem + 10240);
        _Float16 (*Wh)[PADK] = (_Float16(*)[PADK])(smem + 20480);
        _Float16 (*Wl)[PADK] = (_Float16(*)[PADK])(smem + 40960);
        float* qs = (float*)(smem + 61440);
        float* vs = (float*)(smem + 62464);
        float (*spart)[128] = (float(*)[128])(smem + 63488);

        const int l = tid & 63;
        const int w = tid >> 6;
        const int wm = w >> 2, wn = w & 3;
        const int g = l >> 4, li = l & 15;

        if (isow) {
            if (tid < 256) vs[tid] = v_w[tid];
        } else {
            if (tid < 256) qs[tid] = q2v[(size_t)batt * cD + tid];
            else           vs[tid - 256] = v2_w[tid - 256];
        }

        const int ar = tid >> 2, aq = tid & 3;
        size_t arow;
        if (isow) {
            const int m = m0 + ar;
            const int bq = m / L1OW;
            const int s = S1OW + (m - bq * L1OW);
            arow = ((size_t)bq * cS + s) * cD;
        } else {
            arow = ((size_t)batt * cS + S2AT + ar) * cD;
        }

        f32x4 acc[4][4];
#pragma unroll
        for (int mi = 0; mi < 4; ++mi)
#pragma unroll
            for (int ni = 0; ni < 4; ++ni) acc[mi][ni] = (f32x4){0.f, 0.f, 0.f, 0.f};

        for (int k0 = 0; k0 < 256; k0 += 32) {
            __syncthreads();
            *(uint4*)&Ah[ar][aq * 8] = *(const uint4*)&Ahi[arow + k0 + aq * 8];
            *(uint4*)&Al[ar][aq * 8] = *(const uint4*)&Alo[arow + k0 + aq * 8];
            *(uint4*)&Wh[ar][aq * 8] = *(const uint4*)&Whi[(size_t)ar * cD + k0 + aq * 8];
            *(uint4*)&Wl[ar][aq * 8] = *(const uint4*)&Wlo[(size_t)ar * cD + k0 + aq * 8];
            *(uint4*)&Wh[ar + 128][aq * 8] = *(const uint4*)&Whi[(size_t)(ar + 128) * cD + k0 + aq * 8];
            *(uint4*)&Wl[ar + 128][aq * 8] = *(const uint4*)&Wlo[(size_t)(ar + 128) * cD + k0 + aq * 8];
            __syncthreads();

            half8_t ah[4], al[4];
#pragma unroll
            for (int mi = 0; mi < 4; ++mi) {
                ah[mi] = *(const half8_t*)&Ah[wm * 64 + mi * 16 + li][g * 8];
                al[mi] = *(const half8_t*)&Al[wm * 64 + mi * 16 + li][g * 8];
            }
#pragma unroll
            for (int ni = 0; ni < 4; ++ni) {
                const half8_t bh = *(const half8_t*)&Wh[wn * 64 + ni * 16 + li][g * 8];
                const half8_t bl = *(const half8_t*)&Wl[wn * 64 + ni * 16 + li][g * 8];
#pragma unroll
                for (int mi = 0; mi < 4; ++mi) {
                    acc[mi][ni] = __builtin_amdgcn_mfma_f32_16x16x32_f16(ah[mi], bh, acc[mi][ni], 0, 0, 0);
                    acc[mi][ni] = __builtin_amdgcn_mfma_f32_16x16x32_f16(ah[mi], bl, acc[mi][ni], 0, 0, 0);
                    acc[mi][ni] = __builtin_amdgcn_mfma_f32_16x16x32_f16(al[mi], bh, acc[mi][ni], 0, 0, 0);
                }
            }
        }

        float val = 0.f;
#pragma unroll
        for (int mi = 0; mi < 4; ++mi)
#pragma unroll
            for (int rr = 0; rr < 4; ++rr) {
                const int row = wm * 64 + mi * 16 + g * 4 + rr;
                float p = 0.f;
#pragma unroll
                for (int ni = 0; ni < 4; ++ni) {
                    const int c = wn * 64 + ni * 16 + li;
                    const float qq = isow ? q1v[(size_t)((m0 + row) / L1OW) * cD + c]
                                          : qs[c];
                    p = fmaf(vs[c], tanhf(acc[mi][ni][rr] + qq), p);
                }
                p += __shfl_xor(p, 1);
                p += __shfl_xor(p, 2);
                p += __shfl_xor(p, 4);
                p += __shfl_xor(p, 8);
                if (li == mi * 4 + rr) val = p;
            }
        {
            const int row_out = wm * 64 + (li >> 2) * 16 + g * 4 + (li & 3);
            spart[wn][row_out] = val;
        }
        __syncthreads();
        if (tid < 128) {
            const float o = spart[0][tid] + spart[1][tid] + spart[2][tid] + spart[3][tid];
            if (isow) sc1hi[m0 + tid] = o;
            else      sc2hi[(size_t)batt * L2AT + tid] = o;
        }
    } else {
        // -------------------------- fold branch ---------------------------
        const int fb = blk - 1088;
        const bool isowf = fb < 448;           // 448 = S1OW*cB/128
        const float* __restrict__ C  = isowf ? refC : ref2C;
        const float* __restrict__ qv = isowf ? q1v : q2v;
        const float* __restrict__ vv = isowf ? v_w : v2_w;
        float* __restrict__ outv     = isowf ? sc1lo : sc2lo;
        const int m0 = (isowf ? fb : fb - 448) * 128;

        float (*red)[4] = (float(*)[4])smem;
        const int r = tid >> 2, p2 = tid & 3;
        const int m = m0 + r;
        const int b = m & 511;

        const float* row  = C + (size_t)m * cD + p2 * 64;
        const float* qrow = qv + (size_t)b * cD + p2 * 64;
        const float* vrow = vv + p2 * 64;
        float s = 0.f;
#pragma unroll 4
        for (int d = 0; d < 64; d += 4) {
            const float4 rv4 = *(const float4*)&row[d];
            const float4 q4  = *(const float4*)&qrow[d];
            const float4 v4  = *(const float4*)&vrow[d];
            s = fmaf(v4.x, tanhf(rv4.x + q4.x), s);
            s = fmaf(v4.y, tanhf(rv4.y + q4.y), s);
            s = fmaf(v4.z, tanhf(rv4.z + q4.z), s);
            s = fmaf(v4.w, tanhf(rv4.w + q4.w), s);
        }
        red[r][p2] = s;
        __syncthreads();
        if (tid < 128)
            outv[m0 + tid] = red[tid][0] + red[tid][1] + red[tid][2] + red[tid][3];
    }
}

// ---------------------------------------------------------------------------
// Decoder LSTM cells. grid = 256, block = 512.
// ---------------------------------------------------------------------------
__global__ __launch_bounds__(512, 2) void k_dec_cells(
    const float* __restrict__ dec_in,
    const float* __restrict__ Wih_f, const float* __restrict__ Whh_f, const float* __restrict__ b_f,
    const float* __restrict__ Wih_b, const float* __restrict__ Whh_b, const float* __restrict__ b_b,
    float* __restrict__ h_state, float* __restrict__ c_state, float* __restrict__ dec_out)
{
    const int cell = blockIdx.x >> 7;
    const int b0 = (blockIdx.x & 127) * 4;
    const float* __restrict__ Wih = cell ? Wih_b : Wih_f;
    const float* __restrict__ Whh = cell ? Whh_b : Whh_f;
    const float* __restrict__ bv  = cell ? b_b   : b_f;
    const int j = threadIdx.x;

    __shared__ __align__(16) float xin[4][cD];
    __shared__ __align__(16) float hin[4][cH];
    __shared__ __align__(16) float gbuf[4][cG];

    for (int idx = j; idx < 4 * cD; idx += 512) {
        int bb = idx >> 8, k = idx & 255;
        xin[bb][k] = dec_in[(size_t)(b0 + bb) * cD + k];
    }
    {
        int bb = j >> 7, k = j & 127;
        hin[bb][k] = h_state[((size_t)cell * cB + b0 + bb) * cH + k];
    }
    __syncthreads();

    float a0 = bv[j];
    float a1 = a0, a2 = a0, a3 = a0;
#pragma unroll 4
    for (int kk = 0; kk < 64; ++kk) {
        const float4 wv = *(const float4*)&Wih[(size_t)j * cD + kk * 4];
        const float4 x0 = *(const float4*)&xin[0][kk * 4]; DOT4(a0, wv, x0);
        const float4 x1 = *(const float4*)&xin[1][kk * 4]; DOT4(a1, wv, x1);
        const float4 x2 = *(const float4*)&xin[2][kk * 4]; DOT4(a2, wv, x2);
        const float4 x3 = *(const float4*)&xin[3][kk * 4]; DOT4(a3, wv, x3);
    }
#pragma unroll 4
    for (int kk = 0; kk < 32; ++kk) {
        const float4 wv = *(const float4*)&Whh[(size_t)j * cH + kk * 4];
        const float4 h0 = *(const float4*)&hin[0][kk * 4]; DOT4(a0, wv, h0);
        const float4 h1 = *(const float4*)&hin[1][kk * 4]; DOT4(a1, wv, h1);
        const float4 h2 = *(const float4*)&hin[2][kk * 4]; DOT4(a2, wv, h2);
        const float4 h3 = *(const float4*)&hin[3][kk * 4]; DOT4(a3, wv, h3);
    }
    gbuf[0][j] = a0; gbuf[1][j] = a1; gbuf[2][j] = a2; gbuf[3][j] = a3;
    __syncthreads();

    const int uk = j & 127, ub = j >> 7;
    const float gi = gbuf[ub][uk];
    const float gf = gbuf[ub][128 + uk];
    const float gg = gbuf[ub][256 + uk];
    const float go = gbuf[ub][384 + uk];
    const size_t sidx = ((size_t)cell * cB + b0 + ub) * cH + uk;
    const float c_old = c_state[sidx];
    const float i_ = sigmf(gi), f_ = sigmf(gf), g_ = tanhf(gg), o_ = sigmf(go);
    const float cn = fmaf(f_, c_old, i_ * g_);
    const float hn = o_ * tanhf(cn);
    c_state[sidx] = cn;
    h_state[sidx] = hn;
    dec_out[(size_t)(b0 + ub) * cD + cell * cH + uk] = hn;
}

// ---------------------------------------------------------------------------
// q projections. grid 512 (per b), block 256.
// ---------------------------------------------------------------------------
__global__ __launch_bounds__(256, 2) void k_qproj(
    const float* __restrict__ dec_out, const float* __restrict__ dec_in_old,
    const float* __restrict__ W_q, const float* __restrict__ W_q2,
    float* __restrict__ q1v, float* __restrict__ q2v)
{
    const int b = blockIdx.x;
    const int tid = threadIdx.x;
    __shared__ __align__(16) float dout[cD];
    __shared__ __align__(16) float din[cD];
    dout[tid] = dec_out[(size_t)b * cD + tid];
    din[tid]  = dec_in_old[(size_t)b * cD + tid];
    __syncthreads();
    float s1 = 0.0f, s2 = 0.0f;
#pragma unroll 4
    for (int kk = 0; kk < 64; ++kk) {
        const float4 w1 = *(const float4*)&W_q[(size_t)tid * cD + kk * 4];
        const float4 w2 = *(const float4*)&W_q2[(size_t)tid * cD + kk * 4];
        const float4 x1 = *(const float4*)&dout[kk * 4];
        const float4 x2 = *(const float4*)&din[kk * 4];
        DOT4(s1, w1, x1);
        DOT4(s2, w2, x2);
    }
    q1v[(size_t)b * cD + tid] = s1;
    q2v[(size_t)b * cD + tid] = s2;
}

// ---------------------------------------------------------------------------
// Finish step: penalties, ow out, argmax, softmax(att), context (EXACT
// fp16-pair) -> dec_in_new.
// ---------------------------------------------------------------------------
__global__ __launch_bounds__(256, 2) void k_finish(
    const float* __restrict__ sc1lo, const float* __restrict__ sc1hi,
    const float* __restrict__ sc2lo, const float* __restrict__ sc2hi,
    const _Float16* __restrict__ Ehi, const _Float16* __restrict__ Elo,
    const float* __restrict__ s_inputs, const int* __restrict__ s_node_indexes,
    const float* __restrict__ v_input, float* __restrict__ played,
    float* __restrict__ dec_in_new, float* __restrict__ outp, int t)
{
    const int b = blockIdx.x;
    const int tid = threadIdx.x;
    const int lane = tid & 63;
    const int wv = tid >> 6;

    __shared__ __align__(16) float atr[cS];
    __shared__ __align__(16) float part[4][cD];
    __shared__ float rv[cS];
    __shared__ int   ri[cS];

    const float owv = (tid < S1OW) ? sc1lo[(size_t)tid * cB + b]
                                   : sc1hi[(size_t)b * L1OW + (tid - S1OW)];
    atr[tid] = (tid < S2AT) ? sc2lo[(size_t)tid * cB + b]
                            : sc2hi[(size_t)b * L2AT + (tid - S2AT)];

    const float vcpu = v_input[t * 3];
    float val;
    {
        const float a0 = s_inputs[((size_t)b * cS + tid) * 3];
        const float can = (a0 < vcpu ? 1.0f : 0.0f) + played[(size_t)b * cS + tid];
        val = owv - PEN * can;
        outp[2 * cB * cV + ((size_t)t * cB + b) * cS + tid] = val;
    }
    rv[tid] = val; ri[tid] = tid;
    __syncthreads();
#pragma unroll
    for (int off = 128; off > 0; off >>= 1) {
        if (tid < off) {
            const float v2 = rv[tid + off]; const int i2 = ri[tid + off];
            const float v1 = rv[tid];       const int i1 = ri[tid];
            if (v2 > v1 || (v2 == v1 && i2 < i1)) { rv[tid] = v2; ri[tid] = i2; }
        }
        __syncthreads();
    }
    const int sel = ri[0];
    __syncthreads();
    if (tid == 0) {
        played[(size_t)b * cS + sel] += 1.0f;
        outp[(size_t)b * cV + t] = (float)s_node_indexes[(size_t)b * cS + sel];
        outp[(size_t)cB * cV + (size_t)b * cV + t] = (float)sel;
    }

    rv[tid] = atr[tid];
    __syncthreads();
#pragma unroll
    for (int off = 128; off > 0; off >>= 1) {
        if (tid < off) { const float v2 = rv[tid + off]; if (v2 > rv[tid]) rv[tid] = v2; }
        __syncthreads();
    }
    const float mx = rv[0];
    __syncthreads();
    const float ex = expf(atr[tid] - mx);
    rv[tid] = ex;
    __syncthreads();
#pragma unroll
    for (int off = 128; off > 0; off >>= 1) {
        if (tid < off) rv[tid] += rv[tid + off];
        __syncthreads();
    }
    const float ssum = rv[0];
    __syncthreads();
    atr[tid] = ex / ssum;
    __syncthreads();

    {
        float4 acc = make_float4(0.f, 0.f, 0.f, 0.f);
        for (int s2i = wv * 64; s2i < wv * 64 + 64; ++s2i) {
            const float a = atr[s2i];
            const size_t eidx = ((size_t)b * cS + s2i) * cD + lane * 4;
            const half4_t h4 = *(const half4_t*)&Ehi[eidx];
            const half4_t l4 = *(const half4_t*)&Elo[eidx];
            acc.x = fmaf(a, (float)h4[0] + (float)l4[0], acc.x);
            acc.y = fmaf(a, (float)h4[1] + (float)l4[1], acc.y);
            acc.z = fmaf(a, (float)h4[2] + (float)l4[2], acc.z);
            acc.w = fmaf(a, (float)h4[3] + (float)l4[3], acc.w);
        }
        *(float4*)&part[wv][lane * 4] = acc;
    }
    __syncthreads();
    dec_in_new[(size_t)b * cD + tid] =
        part[0][tid] + part[1][tid] + part[2][tid] + part[3][tid];
}

// ---------------------------------------------------------------------------
extern "C" void kernel_launch(void* const* d_in, const int* in_sizes, int n_in,
                              void* d_out, int out_size, void* d_ws, size_t ws_size,
                              hipStream_t stream)
{
    (void)in_sizes; (void)n_in; (void)out_size; (void)ws_size;

    const int*   s_node = (const int*)  d_in[0];
    const float* s_inp  = (const float*)d_in[1];
    const float* v_inp  = (const float*)d_in[2];
    const float* W_emb  = (const float*)d_in[3];
    const float* eWih_f = (const float*)d_in[4];
    const float* eWhh_f = (const float*)d_in[5];
    const float* eb_f   = (const float*)d_in[6];
    const float* eWih_b = (const float*)d_in[7];
    const float* eWhh_b = (const float*)d_in[8];
    const float* eb_b   = (const float*)d_in[9];
    const float* dWih_f = (const float*)d_in[10];
    const float* dWhh_f = (const float*)d_in[11];
    const float* db_f   = (const float*)d_in[12];
    const float* dWih_b = (const float*)d_in[13];
    const float* dWhh_b = (const float*)d_in[14];
    const float* db_b   = (const float*)d_in[15];
    const float* W_ref  = (const float*)d_in[16];
    const float* W_q    = (const float*)d_in[17];
    const float* v_w    = (const float*)d_in[18];
    const float* W_ref2 = (const float*)d_in[19];
    const float* W_q2   = (const float*)d_in[20];
    const float* v2_w   = (const float*)d_in[21];

    float* out = (float*)d_out;
    const size_t ENCSZ = (size_t)cB * cS * cD;     // 33,554,432 elements
    const size_t SMALL = (size_t)cB * cD;          // 131,072 floats

    // layout (bytes), total ~253.5 MiB <= 255 MiB:
    // Ehi 67.1M | Elo 67.1M | refC(fp32,s<112) 58.7M | ref2C(fp32,s<128) 67.1M
    char* p = (char*)d_ws;
    _Float16* Ehi  = (_Float16*)p; p += ENCSZ * 2;
    _Float16* Elo  = (_Float16*)p; p += ENCSZ * 2;
    float* refC    = (float*)p;    p += (size_t)S1OW * cB * cD * 4;
    float* ref2C   = (float*)p;    p += (size_t)S2AT * cB * cD * 4;
    _Float16* Whi1 = (_Float16*)p; p += (size_t)cD * cD * 2;
    _Float16* Wlo1 = (_Float16*)p; p += (size_t)cD * cD * 2;
    _Float16* Whi2 = (_Float16*)p; p += (size_t)cD * cD * 2;
    _Float16* Wlo2 = (_Float16*)p; p += (size_t)cD * cD * 2;
    float* hst    = (float*)p; p += SMALL * 4;
    float* cst    = (float*)p; p += SMALL * 4;
    float* din0   = (float*)p; p += SMALL * 4;
    float* din1   = (float*)p; p += SMALL * 4;
    float* doutb  = (float*)p; p += SMALL * 4;
    float* played = (float*)p; p += SMALL * 4;
    float* q1v    = (float*)p; p += SMALL * 4;
    float* q2v    = (float*)p; p += SMALL * 4;
    float* sc1lo  = (float*)p; p += (size_t)S1OW * cB * 4;
    float* sc1hi  = (float*)p; p += (size_t)L1OW * cB * 4;
    float* sc2lo  = (float*)p; p += (size_t)S2AT * cB * 4;
    float* sc2hi  = (float*)p; p += (size_t)L2AT * cB * 4;
    float* uvec   = (float*)p; p += 2 * cG * 4;

    hipMemsetAsync(played, 0, SMALL * sizeof(float), stream);
    hipMemsetAsync(din0,   0, SMALL * sizeof(float), stream);

    k_split_w<<<256, 256, 0, stream>>>(W_ref, W_ref2, Whi1, Wlo1, Whi2, Wlo2);
    k_uprep<<<2, 512, 0, stream>>>(eWih_f, eWih_b, W_emb, uvec);

    k_encoder<<<256, 1024, 0, stream>>>(s_inp, uvec, eWhh_f, eb_f, eWhh_b, eb_b,
                                        Ehi, Elo, hst, cst);

    // one-time fp32 caches, both heads in one launch (bit-exact)
    k_head_mat2<<<(S1OW + S2AT) * cB / 64, 256, 0, stream>>>(
        Ehi, Elo, Whi1, Wlo1, Whi2, Wlo2, refC, ref2C);

    for (int t = 0; t < cV; ++t) {
        float* di_old = (t & 1) ? din1 : din0;
        float* di_new = (t & 1) ? din0 : din1;
        k_dec_cells<<<256, 512, 0, stream>>>(di_old, dWih_f, dWhh_f, db_f,
                                             dWih_b, dWhh_b, db_b, hst, cst, doutb);
        k_qproj<<<512, 256, 0, stream>>>(doutb, di_old, W_q, W_q2, q1v, q2v);
        k_score<<<2048, 512, 0, stream>>>(Ehi, Elo, Whi1, Wlo1, Whi2, Wlo2,
                                          refC, ref2C, q1v, q2v, v_w, v2_w,
                                          sc1lo, sc1hi, sc2lo, sc2hi);
        k_finish<<<512, 256, 0, stream>>>(sc1lo, sc1hi, sc2lo, sc2hi, Ehi, Elo,
                                          s_inp, s_node, v_inp, played, di_new, out, t);
    }
}